// Round 6
// baseline (25.172 us; speedup 1.0000x reference)
//
#include <hip/hip_runtime.h>

// Polyphase resampler 16000 -> 14400 Hz (SpeedPerturb).
// stride 10, P = 9 phases, W = 14 taps.
// Thread owns FOUR periods k -> outputs t = 36k+j, j=0..35.
// Window = wav[40k-8 .. 40k+47] (56 floats); 40k-8 is 16B-aligned ->
// 14 static float4 loads. o_j = OFF[j%9] + 2 + 10*(j/9), OFF =
// {0,1,2,3,4,5,6,8,9}; max o+13 = 54 < 56. Output slab 36k is 16B-aligned
// -> 9 static float4 stores. No LDS, no barriers: pure streaming.

#define RS_TPB 256
#define RS_G 4
#define RS_OPT (RS_G * 9)   // 36 outputs / thread
#define RS_WIN 56

__global__ __launch_bounds__(RS_TPB) void resample_kernel(
    const float* __restrict__ wav, const float* __restrict__ wgt,
    float* __restrict__ out, int N, int K, int TOT) {
  const int b = blockIdx.y;
  const int k = blockIdx.x * RS_TPB + threadIdx.x;
  if (k >= K) return;

  const float* __restrict__ wrow = wav + (size_t)b * N;
  const int abase = 40 * k - 8;

  float win[RS_WIN];
  if (abase >= 0 && abase + RS_WIN <= N) {
#pragma unroll
    for (int r = 0; r < RS_WIN / 4; ++r) {
      const float4 v = *reinterpret_cast<const float4*>(wrow + abase + (r << 2));
      win[4 * r + 0] = v.x;
      win[4 * r + 1] = v.y;
      win[4 * r + 2] = v.z;
      win[4 * r + 3] = v.w;
    }
  } else {
#pragma unroll
    for (int i = 0; i < RS_WIN; ++i) {
      const int gi = abase + i;
      win[i] = (gi >= 0 && gi < N) ? wrow[gi] : 0.0f;
    }
  }

  const int OFF[9] = {0, 1, 2, 3, 4, 5, 6, 8, 9};
  float* __restrict__ orow = out + (size_t)b * TOT + (size_t)k * RS_OPT;
#pragma unroll
  for (int g = 0; g < RS_OPT / 4; ++g) {     // 9 groups of 4 outputs
    float4 o;
    float* po = &o.x;
#pragma unroll
    for (int q = 0; q < 4; ++q) {
      const int j = 4 * g + q;                          // compile-time
      const int oidx = OFF[j % 9] + 2 + 10 * (j / 9);   // compile-time
      const float* wp = &wgt[14 * (j % 9)];
      float acc = 0.0f;
#pragma unroll
      for (int w = 0; w < 14; ++w) acc = fmaf(win[oidx + w], wp[w], acc);
      po[q] = acc;
    }
    *reinterpret_cast<float4*>(orow + (g << 2)) = o;
  }
}

extern "C" void kernel_launch(void* const* d_in, const int* in_sizes, int n_in,
                              void* d_out, int out_size, void* d_ws, size_t ws_size,
                              hipStream_t stream) {
  const float* wav = (const float*)d_in[0];
  const float* wgt = (const float*)d_in[1];
  float* out = (float*)d_out;

  const int N = 480000;
  const int B = in_sizes[0] / N;    // 16
  const int TOT = out_size / B;     // 432000
  const int K = (TOT + RS_OPT - 1) / RS_OPT;  // 12000 (exact: 36*12000)

  dim3 grid((K + RS_TPB - 1) / RS_TPB, B);
  resample_kernel<<<grid, RS_TPB, 0, stream>>>(wav, wgt, out, N, K, TOT);
}

// Round 7
// 18.446 us; speedup vs baseline: 1.3646x; 1.3646x over previous
//
#include <hip/hip_runtime.h>

// Polyphase resampler 16000 -> 14400 Hz (SpeedPerturb).
// stride 10, P = 9 phases, W = 14 taps.
// WAVE-LOCAL structure, no block barriers:
//   wave handles 64 consecutive periods m = base..base+63 (outputs 9m..9m+8).
//   Stage wav[10*base-16 .. +768) into this wave's LDS region with 3
//   coalesced global_load_lds x16B; per-wave vmcnt(0); windows read back as
//   12x ds_read_b64 (float2-unit lane-stride 5, gcd(5,16)=1 -> b64 bank
//   floor, conflict-free). 9 outputs restaged (stride-9 b32 = 2-way = free),
//   stored as coalesced float4. Edge waves use guarded scalar staging.

#define RS_TPB 256
#define RS_WPB 4
#define RS_SPANF 768   // floats staged per wave (need <= 664)

typedef __attribute__((address_space(1))) const void gvoid_t;
typedef __attribute__((address_space(3))) void lvoid_t;

__global__ __launch_bounds__(RS_TPB) void resample_kernel(
    const float* __restrict__ wav, const float* __restrict__ wgt,
    float* __restrict__ out, int N, int M, int TOT) {
  __shared__ __align__(16) float s_in[RS_WPB][RS_SPANF];   // 12288 B
  __shared__ __align__(16) float s_out[RS_WPB][576];       //  9216 B

  const int b = blockIdx.y;
  const int tid = threadIdx.x;
  const int w = tid >> 6;
  const int lane = tid & 63;
  const int base = blockIdx.x * RS_TPB + w * 64;  // first period of this wave
  if (base >= M) return;                          // M % 64 == 0: full waves only

  const float* __restrict__ wrow = wav + (size_t)b * N;
  const int astart = 10 * base - 16;              // 16B-aligned (10*base % 16 == 0)

  const bool interior = (astart >= 0) && (astart + RS_SPANF <= N);
  if (interior) {
#pragma unroll
    for (int it = 0; it < 3; ++it) {
      __builtin_amdgcn_global_load_lds(
          (gvoid_t*)(wrow + astart + it * 256 + lane * 4),
          (lvoid_t*)&s_in[w][it * 256], 16, 0, 0);
    }
    asm volatile("s_waitcnt vmcnt(0)" ::: "memory");  // per-wave drain only
  } else {
    for (int i = lane; i < RS_SPANF; i += 64) {
      const int gi = astart + i;
      s_in[w][i] = (gi >= 0 && gi < N) ? wrow[gi] : 0.0f;
    }
  }
  __builtin_amdgcn_wave_barrier();

  // Window: floats [10*lane+10, 10*lane+33] of this wave's region.
  float win[24];
  const float2* s2 = reinterpret_cast<const float2*>(&s_in[w][0]);
  const int d0 = 5 * lane + 5;
#pragma unroll
  for (int r = 0; r < 12; ++r) {
    const float2 v = s2[d0 + r];
    win[2 * r] = v.x;
    win[2 * r + 1] = v.y;
  }

  const int OFF[9] = {0, 1, 2, 3, 4, 5, 6, 8, 9};
#pragma unroll
  for (int j = 0; j < 9; ++j) {
    const float* wp = &wgt[14 * j];
    float acc = 0.0f;
#pragma unroll
    for (int t = 0; t < 14; ++t) acc = fmaf(win[OFF[j] + t], wp[t], acc);
    s_out[w][lane * 9 + j] = acc;
  }
  __builtin_amdgcn_wave_barrier();

  // Coalesced float4 store of this wave's 576 contiguous outputs.
  float* __restrict__ orow = out + (size_t)b * TOT + (size_t)base * 9;
  const float4* so4 = reinterpret_cast<const float4*>(&s_out[w][0]);
#pragma unroll
  for (int it = 0; it < 3; ++it) {
    const int i4 = it * 64 + lane;
    if (i4 < 144) *reinterpret_cast<float4*>(orow + 4 * i4) = so4[i4];
  }
}

extern "C" void kernel_launch(void* const* d_in, const int* in_sizes, int n_in,
                              void* d_out, int out_size, void* d_ws, size_t ws_size,
                              hipStream_t stream) {
  const float* wav = (const float*)d_in[0];
  const float* wgt = (const float*)d_in[1];
  float* out = (float*)d_out;

  const int N = 480000;
  const int B = in_sizes[0] / N;   // 16
  const int TOT = out_size / B;    // 432000
  const int M = (TOT + 8) / 9;     // 48000 periods (multiple of 64)

  dim3 grid((M + RS_TPB - 1) / RS_TPB, B);
  resample_kernel<<<grid, RS_TPB, 0, stream>>>(wav, wgt, out, N, M, TOT);
}

// Round 8
// 15.821 us; speedup vs baseline: 1.5910x; 1.1659x over previous
//
#include <hip/hip_runtime.h>

// Polyphase resampler 16000 -> 14400 Hz (SpeedPerturb).
// stride 10, P = 9 phases, W = 14 taps.
// R3 backbone (direct scattered float2 window loads, register compute),
// but FULLY WAVE-DECOUPLED: per-wave s_out region, no __syncthreads.
// Wave owns 64 periods m = wbase..wbase+63 (outputs 9m..9m+8).
// out[9m+j] = sum_w wav[10m-6+OFF[j]+w]*wgt[14j+w], OFF={0,1,2,3,4,5,6,8,9}.
// M % 64 == 0 and TOT == 9*M exactly -> no tail anywhere.

#define RS_TPB 256

__global__ __launch_bounds__(RS_TPB) void resample_kernel(
    const float* __restrict__ wav, const float* __restrict__ wgt,
    float* __restrict__ out, int N, int M, int TOT) {
  __shared__ __align__(16) float s_out[4][576];   // per-wave 2304 B

  const int b = blockIdx.y;
  const int tid = threadIdx.x;
  const int w = tid >> 6;
  const int lane = tid & 63;
  const int wbase = blockIdx.x * RS_TPB + (w << 6);  // first period of wave
  if (wbase >= M) return;            // wave-uniform exit; no block barrier exists

  const int m = wbase + lane;
  const float* __restrict__ wrow = wav + (size_t)b * N;

  // Window: wav[10m-6 .. 10m+17] (24 floats), 8B-aligned (10m-6 even).
  const int gbase = 10 * m - 6;
  float win[24];
  if (gbase >= 0 && gbase + 24 <= N) {
#pragma unroll
    for (int r = 0; r < 12; ++r) {
      const float2 v = *reinterpret_cast<const float2*>(wrow + gbase + 2 * r);
      win[2 * r] = v.x;
      win[2 * r + 1] = v.y;
    }
  } else {
#pragma unroll
    for (int i = 0; i < 24; ++i) {
      const int gi = gbase + i;
      win[i] = (gi >= 0 && gi < N) ? wrow[gi] : 0.0f;
    }
  }

  const int OFF[9] = {0, 1, 2, 3, 4, 5, 6, 8, 9};
#pragma unroll
  for (int j = 0; j < 9; ++j) {
    const float* wp = &wgt[14 * j];
    float acc = 0.0f;
#pragma unroll
    for (int t = 0; t < 14; ++t) acc = fmaf(win[OFF[j] + t], wp[t], acc);
    s_out[w][lane * 9 + j] = acc;   // stride-9 b32: gcd(9,32)=1 -> conflict-free
  }
  __builtin_amdgcn_wave_barrier();  // same-wave order; lgkmcnt by compiler

  // Coalesced float4 store of this wave's 576 contiguous outputs.
  float* __restrict__ orow = out + (size_t)b * TOT + (size_t)wbase * 9;
  const float4* so4 = reinterpret_cast<const float4*>(&s_out[w][0]);
#pragma unroll
  for (int it = 0; it < 3; ++it) {
    const int i4 = it * 64 + lane;
    if (i4 < 144) *reinterpret_cast<float4*>(orow + (i4 << 2)) = so4[i4];
  }
}

extern "C" void kernel_launch(void* const* d_in, const int* in_sizes, int n_in,
                              void* d_out, int out_size, void* d_ws, size_t ws_size,
                              hipStream_t stream) {
  const float* wav = (const float*)d_in[0];
  const float* wgt = (const float*)d_in[1];
  float* out = (float*)d_out;

  const int N = 480000;
  const int B = in_sizes[0] / N;   // 16
  const int TOT = out_size / B;    // 432000
  const int M = (TOT + 8) / 9;     // 48000 periods (multiple of 64)

  dim3 grid((M + RS_TPB - 1) / RS_TPB, B);
  resample_kernel<<<grid, RS_TPB, 0, stream>>>(wav, wgt, out, N, M, TOT);
}